// Round 2
// baseline (1994.223 us; speedup 1.0000x reference)
//
#include <hip/hip_runtime.h>
#include <stdint.h>

// Problem constants (from reference): B=4, S=2048, IN=4096, OUT=16384
#define M_DIM 8192   // B*S
#define N_DIM 16384  // OUT
#define K_DIM 4096   // IN

typedef __bf16 bf16x8 __attribute__((ext_vector_type(8)));
typedef float f32x4 __attribute__((ext_vector_type(4)));
typedef unsigned short u16x8 __attribute__((ext_vector_type(8)));

// fp32 -> bf16 bits, round-to-nearest-even (inputs are finite normals; no NaN care)
__device__ inline unsigned short f2bf(float f) {
    union { float f; unsigned u; } v; v.f = f;
    unsigned u = v.u;
    return (unsigned short)((u + 0x7fffu + ((u >> 16) & 1u)) >> 16);
}

// async global->LDS, 16 bytes per lane; LDS dest = wave-uniform base + lane*16
#define GLDS16(gp, lp)                                                            \
    __builtin_amdgcn_global_load_lds(                                             \
        (const __attribute__((address_space(1))) void*)(gp),                      \
        (__attribute__((address_space(3))) void*)(lp), 16, 0, 0)

// ---------------------------------------------------------------------------
// Prepass 1: x fp32 -> bf16 bits, plus per-row sum (for the zero-point term).
// One block per row of 4096.
// ---------------------------------------------------------------------------
__global__ __launch_bounds__(256) void convert_x_kernel(
    const float* __restrict__ x, unsigned short* __restrict__ xb,
    float* __restrict__ rowsum) {
    const int row = blockIdx.x;
    const float4* xr = (const float4*)(x + (size_t)row * K_DIM);
    ushort4* xo = (ushort4*)(xb + (size_t)row * K_DIM);
    float s = 0.f;
#pragma unroll
    for (int it = 0; it < 4; ++it) {
        int i = threadIdx.x + it * 256;  // 1024 float4 chunks per row
        float4 v = xr[i];
        s += v.x + v.y + v.z + v.w;
        ushort4 o;
        o.x = f2bf(v.x); o.y = f2bf(v.y); o.z = f2bf(v.z); o.w = f2bf(v.w);
        xo[i] = o;
    }
    __shared__ float red[256];
    red[threadIdx.x] = s;
    __syncthreads();
    for (int off = 128; off > 0; off >>= 1) {
        if (threadIdx.x < off) red[threadIdx.x] += red[threadIdx.x + off];
        __syncthreads();
    }
    if (threadIdx.x == 0) rowsum[row] = red[0];
}

// ---------------------------------------------------------------------------
// Prepass 2: weight int32 (one quantized value per int, per harness "integer
// -> const int*" contract) -> bf16 bits. Values in [-128,127] are exact in
// bf16. 8 weights per thread: 2x int4 load -> 1x u16x8 store.
// ---------------------------------------------------------------------------
__global__ __launch_bounds__(256) void convert_w_kernel(
    const int* __restrict__ wq, unsigned short* __restrict__ wb) {
    const size_t t = (size_t)blockIdx.x * 256 + threadIdx.x;  // 8 weights/thread
    const int4* p = (const int4*)wq + t * 2;
    int4 a = p[0], b = p[1];
    u16x8 o;
    o[0] = f2bf((float)a.x); o[1] = f2bf((float)a.y);
    o[2] = f2bf((float)a.z); o[3] = f2bf((float)a.w);
    o[4] = f2bf((float)b.x); o[5] = f2bf((float)b.y);
    o[6] = f2bf((float)b.z); o[7] = f2bf((float)b.w);
    ((u16x8*)wb)[t] = o;
}

// ---------------------------------------------------------------------------
// Main GEMM: C[m][n] = scale[n] * (A.q  dot) - scale[n]*zp[n]*rowsum[m] + bias[n]
// A: M x K bf16 (x converted), B: N x K bf16 (weights converted) -> NT GEMM.
// 128x128 tile, BK=32, 256 threads (4 waves, 2x2 of 64x64), 16x16x32 MFMA.
// m97 structure: global_load_lds width=16, 2-barrier K-loop.
// ---------------------------------------------------------------------------
__global__ __launch_bounds__(256) void gemm_kernel(
    const unsigned short* __restrict__ A, const unsigned short* __restrict__ B,
    const float* __restrict__ rowsum, const float* __restrict__ scale,
    const float* __restrict__ zp, const float* __restrict__ bias,
    float* __restrict__ C) {
    __shared__ __align__(16) unsigned short As[128 * 32];  // 8 KB, row-major [128][32]
    __shared__ __align__(16) unsigned short Bs[128 * 32];  // 8 KB

    const int t = threadIdx.x;
    const int w = t >> 6;   // wave 0..3
    const int l = t & 63;   // lane

    const int tileN = blockIdx.x * 128;
    const int tileM = blockIdx.y * 128;

    // --- staging coords: lane l of wave w covers row (w*16 + l/4), k-chunk (l%4)*8
    const int srow = (w << 4) + (l >> 2);
    const int scol = (l & 3) << 3;
    const unsigned short* ga0 = A + (size_t)(tileM + srow) * K_DIM + scol;
    const unsigned short* ga1 = ga0 + (size_t)64 * K_DIM;
    const unsigned short* gb0 = B + (size_t)(tileN + srow) * K_DIM + scol;
    const unsigned short* gb1 = gb0 + (size_t)64 * K_DIM;
    // wave-uniform LDS bases (HW adds lane*16 bytes)
    unsigned short* lA0 = As + w * 512;
    unsigned short* lA1 = As + 2048 + w * 512;
    unsigned short* lB0 = Bs + w * 512;
    unsigned short* lB1 = Bs + 2048 + w * 512;

    // --- fragment coords
    const int wm = w & 1, wn = w >> 1;
    const int lcol = l & 15, lk = l >> 4;
    const unsigned short* apf = As + (size_t)(wm * 64 + lcol) * 32 + lk * 8;
    const unsigned short* bpf = Bs + (size_t)(wn * 64 + lcol) * 32 + lk * 8;

    f32x4 acc[4][4];
#pragma unroll
    for (int i = 0; i < 4; ++i)
#pragma unroll
        for (int j = 0; j < 4; ++j) acc[i][j] = f32x4{0.f, 0.f, 0.f, 0.f};

    for (int k0 = 0; k0 < K_DIM; k0 += 32) {
        GLDS16(ga0, lA0);
        GLDS16(ga1, lA1);
        GLDS16(gb0, lB0);
        GLDS16(gb1, lB1);
        ga0 += 32; ga1 += 32; gb0 += 32; gb1 += 32;
        __syncthreads();  // drains glds (vmcnt(0)) + barrier

        bf16x8 af[4], bf[4];
#pragma unroll
        for (int i = 0; i < 4; ++i) af[i] = *(const bf16x8*)(apf + i * 512);
#pragma unroll
        for (int i = 0; i < 4; ++i) bf[i] = *(const bf16x8*)(bpf + i * 512);
#pragma unroll
        for (int mi = 0; mi < 4; ++mi)
#pragma unroll
            for (int ni = 0; ni < 4; ++ni)
                acc[mi][ni] = __builtin_amdgcn_mfma_f32_16x16x32_bf16(
                    af[mi], bf[ni], acc[mi][ni], 0, 0, 0);
        __syncthreads();  // protect LDS tile from next iteration's staging
    }

    // --- epilogue: C/D layout col=lane&15, row=(lane>>4)*4+reg
    const int nb = tileN + wn * 64 + lcol;
    float sc[4], szp[4], bs[4];
#pragma unroll
    for (int ni = 0; ni < 4; ++ni) {
        int n = nb + ni * 16;
        float s = scale[n];
        sc[ni] = s;
        szp[ni] = s * zp[n];
        bs[ni] = bias[n];
    }
    const int mb = tileM + wm * 64 + lk * 4;
#pragma unroll
    for (int mi = 0; mi < 4; ++mi) {
#pragma unroll
        for (int i = 0; i < 4; ++i) {
            int m = mb + mi * 16 + i;
            float rs = rowsum[m];
            float* orow = C + (size_t)m * N_DIM + nb;
#pragma unroll
            for (int ni = 0; ni < 4; ++ni)
                orow[ni * 16] = acc[mi][ni][i] * sc[ni] + bs[ni] - szp[ni] * rs;
        }
    }
}

// ---------------------------------------------------------------------------
// Fallback (only if ws_size is too small for the bf16 conversions):
// simple fp32 LDS-tiled GEMM, correct but slow. Weights are int32/element.
// ---------------------------------------------------------------------------
__global__ __launch_bounds__(256) void fallback_kernel(
    const float* __restrict__ x, const int* __restrict__ wq,
    const float* __restrict__ scale, const float* __restrict__ zp,
    const float* __restrict__ bias, float* __restrict__ C) {
    __shared__ float Asf[64][33];
    __shared__ float Bsf[64][33];
    const int tileM = blockIdx.y * 64, tileN = blockIdx.x * 64;
    const int tx = threadIdx.x & 15, ty = threadIdx.x >> 4;
    float accq[4][4] = {};
    float rsum[4] = {};
    for (int k0 = 0; k0 < K_DIM; k0 += 32) {
        for (int i = threadIdx.x; i < 64 * 32; i += 256) {
            int r = i >> 5, c = i & 31;
            Asf[r][c] = x[(size_t)(tileM + r) * K_DIM + k0 + c];
            Bsf[r][c] = (float)wq[(size_t)(tileN + r) * K_DIM + k0 + c];
        }
        __syncthreads();
        for (int kk = 0; kk < 32; ++kk) {
            float av[4], bv[4];
#pragma unroll
            for (int j = 0; j < 4; ++j) av[j] = Asf[ty * 4 + j][kk];
#pragma unroll
            for (int j = 0; j < 4; ++j) bv[j] = Bsf[tx * 4 + j][kk];
#pragma unroll
            for (int i = 0; i < 4; ++i) {
                rsum[i] += av[i];
#pragma unroll
                for (int j = 0; j < 4; ++j) accq[i][j] += av[i] * bv[j];
            }
        }
        __syncthreads();
    }
#pragma unroll
    for (int i = 0; i < 4; ++i) {
        int m = tileM + ty * 4 + i;
#pragma unroll
        for (int j = 0; j < 4; ++j) {
            int n = tileN + tx * 4 + j;
            C[(size_t)m * N_DIM + n] =
                scale[n] * accq[i][j] - scale[n] * zp[n] * rsum[i] + bias[n];
        }
    }
}

extern "C" void kernel_launch(void* const* d_in, const int* in_sizes, int n_in,
                              void* d_out, int out_size, void* d_ws, size_t ws_size,
                              hipStream_t stream) {
    const float* x = (const float*)d_in[0];
    const int* wq = (const int*)d_in[1];  // int32 per element, N_DIM x K_DIM
    const float* scale = (const float*)d_in[2];
    const float* zp = (const float*)d_in[3];
    const float* bias = (const float*)d_in[4];
    float* out = (float*)d_out;

    const size_t xb_bytes = (size_t)M_DIM * K_DIM * 2;  // 64 MiB
    const size_t wb_bytes = (size_t)N_DIM * K_DIM * 2;  // 128 MiB
    const size_t need = xb_bytes + wb_bytes + (size_t)M_DIM * 4;

    if (ws_size >= need) {
        unsigned short* xb = (unsigned short*)d_ws;
        unsigned short* wb = (unsigned short*)((char*)d_ws + xb_bytes);
        float* rowsum = (float*)((char*)d_ws + xb_bytes + wb_bytes);
        convert_x_kernel<<<M_DIM, 256, 0, stream>>>(x, xb, rowsum);
        const int wblocks = (int)(((size_t)N_DIM * K_DIM) / 8 / 256);  // 32768
        convert_w_kernel<<<wblocks, 256, 0, stream>>>(wq, wb);
        dim3 grid(N_DIM / 128, M_DIM / 128);  // 128 x 64
        gemm_kernel<<<grid, 256, 0, stream>>>(xb, wb, rowsum, scale, zp, bias, out);
    } else {
        dim3 grid(N_DIM / 64, M_DIM / 64);
        fallback_kernel<<<grid, 256, 0, stream>>>(x, wq, scale, zp, bias, out);
    }
}